// Round 2
// baseline (424.234 us; speedup 1.0000x reference)
//
#include <hip/hip_runtime.h>

// SparseMeshConv fused kernel, R1 (MI355X / gfx950)
//   patch = [x, |a-c|, a+c, |b-d|, b+d]  (a=x[idx1], b=x[idx2], c=x[idx3], d=x[idx4])
//   y = LN(patch @ W + bias) * gamma + beta + x;  out = gelu_erf(y)
// R1 changes vs R0:
//  - K-permuted chunk order: (|a-c|_p, a+c_p) adjacent -> gather rows loaded ONCE
//  - XOR-swizzled LDS (no pad), reductions aliased onto A tile -> LDS 40960 B = 4 blocks/CU
//  - W staged via async global_load_lds width-16 (Wt stored pre-swizzled in LDS-image order)
//  - A gather loads software-pipelined across the MFMA section

#define N_ROWS   100000
#define C        256
#define BK       64
#define NCHUNK   20      // 1280 / 64
#define BM       64
#define LN_EPS   1e-5f

typedef __bf16 bf16;
typedef bf16  bf16x8 __attribute__((ext_vector_type(8)));
typedef float f32x4  __attribute__((ext_vector_type(4)));

union BV { bf16x8 v; bf16 h[8]; };
union FV { float4 q[4]; float f[16]; };

__device__ __forceinline__ void async_g2l(const void* g, void* l) {
    __builtin_amdgcn_global_load_lds(
        (const __attribute__((address_space(1))) void*)g,
        (__attribute__((address_space(3))) void*)l, 16, 0, 0);
}

// K-chunk -> original W row permutation:
//  kc 0..3  : x cols            kRow = kc*64 + kk
//  kc 4..11 : u=kc-4, h=u&1, p=u>>1 -> kRow = 256 + h*256 + p*64 + kk   (|a-c| / a+c)
//  kc 12..19: u=kc-12 likewise  kRow = 768 + h*256 + p*64 + kk          (|b-d| / b+d)
// Wt stores bf16 in LDS-image order: [kc][n][granule-slot gs][e], gs = (kk>>3) ^ (n&7)
__global__ void wprep(const float* __restrict__ W, bf16* __restrict__ Wt) {
    int t = blockIdx.x * 256 + threadIdx.x;
    if (t >= NCHUNK * BK * C) return;          // 327680
    int n  = t & 255;                          // coalesced reads over n
    int r  = t >> 8;                           // kc*64 + kk
    int kc = r >> 6;
    int kk = r & 63;
    int kRow;
    if (kc < 4)       kRow = kc * 64 + kk;
    else if (kc < 12) { int u = kc - 4;  kRow = 256 + (u & 1) * 256 + (u >> 1) * 64 + kk; }
    else              { int u = kc - 12; kRow = 768 + (u & 1) * 256 + (u >> 1) * 64 + kk; }
    int gs = (kk >> 3) ^ (n & 7);
    Wt[(size_t)kc * (C * BK) + n * 64 + gs * 8 + (kk & 7)] = (bf16)W[(size_t)kRow * C + n];
}

__global__ __launch_bounds__(256, 4)
void fused(const float* __restrict__ x,
           const int* __restrict__ idx1, const int* __restrict__ idx2,
           const int* __restrict__ idx3, const int* __restrict__ idx4,
           const bf16* __restrict__ Wt,
           const float* __restrict__ bias,
           const float* __restrict__ gamma_, const float* __restrict__ beta_,
           float* __restrict__ out)
{
    __shared__ __align__(16) bf16 Wl[C * BK];           // 32768 B, swizzled image
    __shared__ __align__(16) union {
        bf16 a[BM * BK];                                // 8192 B, swizzled
        struct { float rsum[BM][4]; float rsq[BM][4]; float mu[BM]; float rs[BM]; } red;
    } SA;                                               // total LDS = 40960 -> 4 blocks/CU

    const int tid  = threadIdx.x;
    const int lane = tid & 63;
    const int wv   = tid >> 6;       // wave -> column group (wv*64)
    const int quad = lane >> 4;
    const int l16  = lane & 15;
    const int r0   = blockIdx.x * BM;

    const int r_st = tid >> 2;       // staging row 0..63
    const int q_st = tid & 3;        // 16-float quarter
    int gr_self = r0 + r_st; if (gr_self >= N_ROWS) gr_self = 0;
    const int ia = idx1[gr_self], ib = idx2[gr_self];
    const int ic = idx3[gr_self], id = idx4[gr_self];

    f32x4 acc[4][4] = {};
    bf16x8 st0, st1;                 // staged bf16 for current chunk
    bf16x8 h0, h1;                   // held (a+c)/(b+d) bf16 for odd pair chunk

    // ---- prepare chunk 0 (x cols 0..63)
    {
        const float4* p = (const float4*)(x + (size_t)gr_self * C + (q_st << 4));
        FV u;
        #pragma unroll
        for (int j = 0; j < 4; ++j) u.q[j] = p[j];
        BV b0, b1;
        #pragma unroll
        for (int j = 0; j < 8; ++j) { b0.h[j] = (bf16)u.f[j]; b1.h[j] = (bf16)u.f[j + 8]; }
        st0 = b0.v; st1 = b1.v;
    }

    for (int kc = 0; kc < NCHUNK; ++kc) {
        // ---- write staged A chunk to LDS (swizzled granules)
        {
            int g0 = (2 * q_st)     ^ (r_st & 7);
            int g1 = (2 * q_st + 1) ^ (r_st & 7);
            *(bf16x8*)&SA.a[r_st * 64 + g0 * 8] = st0;
            *(bf16x8*)&SA.a[r_st * 64 + g1 * 8] = st1;
        }
        // ---- async-stage W chunk (global -> LDS, lane-contiguous image)
        {
            const bf16* wsrc = Wt + (size_t)kc * (C * BK);
            #pragma unroll
            for (int j = 0; j < 8; ++j) {
                int g = j * 256 + tid;
                async_g2l(wsrc + g * 8, &Wl[g * 8]);
            }
        }
        __syncthreads();   // drains vmcnt: W landed, A visible

        // ---- issue pipelined gather/self loads for chunk kc+1
        const int kn = kc + 1;
        FV la, lc;
        int mode = 0;      // 0 none/held, 1 x-chunk, 2 even pair chunk
        if (kn < 4) {
            mode = 1;
            const float4* p = (const float4*)(x + (size_t)gr_self * C + (kn << 6) + (q_st << 4));
            #pragma unroll
            for (int j = 0; j < 4; ++j) la.q[j] = p[j];
        } else if (kn < NCHUNK) {
            int u = (kn < 12) ? (kn - 4) : (kn - 12);
            if ((u & 1) == 0) {
                mode = 2;
                int rA = (kn < 12) ? ia : ib;
                int rC = (kn < 12) ? ic : id;
                int off = ((u >> 1) << 6) + (q_st << 4);
                const float4* pa = (const float4*)(x + (size_t)rA * C + off);
                const float4* pc = (const float4*)(x + (size_t)rC * C + off);
                #pragma unroll
                for (int j = 0; j < 4; ++j) { la.q[j] = pa[j]; lc.q[j] = pc[j]; }
            }
        }

        // ---- MFMA: 2 k-steps of 32
        #pragma unroll
        for (int ks = 0; ks < 2; ++ks) {
            const int gbase = ks * 4 + quad;
            bf16x8 af[4], bfr[4];
            #pragma unroll
            for (int mi = 0; mi < 4; ++mi) {
                int m = mi * 16 + l16;
                af[mi] = *(const bf16x8*)&SA.a[m * 64 + ((gbase ^ (m & 7)) * 8)];
            }
            #pragma unroll
            for (int ni = 0; ni < 4; ++ni) {
                int n = wv * 64 + ni * 16 + l16;
                bfr[ni] = *(const bf16x8*)&Wl[n * 64 + ((gbase ^ (n & 7)) * 8)];
            }
            #pragma unroll
            for (int mi = 0; mi < 4; ++mi)
                #pragma unroll
                for (int ni = 0; ni < 4; ++ni)
                    acc[mi][ni] = __builtin_amdgcn_mfma_f32_16x16x32_bf16(
                        af[mi], bfr[ni], acc[mi][ni], 0, 0, 0);
        }

        // ---- finish preparing chunk kc+1 (waits on the pipelined loads here)
        if (mode == 1) {
            BV b0, b1;
            #pragma unroll
            for (int j = 0; j < 8; ++j) { b0.h[j] = (bf16)la.f[j]; b1.h[j] = (bf16)la.f[j + 8]; }
            st0 = b0.v; st1 = b1.v;
        } else if (mode == 2) {
            BV d0, d1, s0, s1;
            #pragma unroll
            for (int j = 0; j < 8; ++j) {
                d0.h[j] = (bf16)fabsf(la.f[j]     - lc.f[j]);
                d1.h[j] = (bf16)fabsf(la.f[j + 8] - lc.f[j + 8]);
                s0.h[j] = (bf16)(la.f[j]     + lc.f[j]);
                s1.h[j] = (bf16)(la.f[j + 8] + lc.f[j + 8]);
            }
            st0 = d0.v; st1 = d1.v; h0 = s0.v; h1 = s1.v;
        } else if (kn < NCHUNK) {
            st0 = h0; st1 = h1;      // odd pair chunk: held sum
        }
        __syncthreads();   // write-after-read guard for next iteration's LDS writes
    }

    // ---- epilogue: +bias, LN stats, normalize, residual, exact GELU
    float bcol[4], gcol[4], ecol[4];
    #pragma unroll
    for (int ni = 0; ni < 4; ++ni) {
        int cidx = wv * 64 + ni * 16 + l16;
        bcol[ni] = bias[cidx]; gcol[ni] = gamma_[cidx]; ecol[ni] = beta_[cidx];
    }
    #pragma unroll
    for (int mi = 0; mi < 4; ++mi)
        #pragma unroll
        for (int ni = 0; ni < 4; ++ni)
            #pragma unroll
            for (int rg = 0; rg < 4; ++rg)
                acc[mi][ni][rg] += bcol[ni];

    #pragma unroll
    for (int mi = 0; mi < 4; ++mi) {
        #pragma unroll
        for (int rg = 0; rg < 4; ++rg) {
            float s = 0.f, q = 0.f;
            #pragma unroll
            for (int ni = 0; ni < 4; ++ni) {
                float y = acc[mi][ni][rg];
                s += y; q += y * y;
            }
            #pragma unroll
            for (int m = 1; m <= 8; m <<= 1) {
                s += __shfl_xor(s, m, 64);
                q += __shfl_xor(q, m, 64);
            }
            if (l16 == 0) {
                int row = mi * 16 + quad * 4 + rg;
                SA.red.rsum[row][wv] = s;
                SA.red.rsq [row][wv] = q;
            }
        }
    }
    __syncthreads();
    if (tid < BM) {
        float s  = SA.red.rsum[tid][0] + SA.red.rsum[tid][1] + SA.red.rsum[tid][2] + SA.red.rsum[tid][3];
        float q  = SA.red.rsq [tid][0] + SA.red.rsq [tid][1] + SA.red.rsq [tid][2] + SA.red.rsq [tid][3];
        float mu = s * (1.0f / C);
        float var = q * (1.0f / C) - mu * mu;
        SA.red.mu[tid] = mu;
        SA.red.rs[tid] = rsqrtf(var + LN_EPS);
    }
    __syncthreads();

    #pragma unroll
    for (int mi = 0; mi < 4; ++mi) {
        #pragma unroll
        for (int rg = 0; rg < 4; ++rg) {
            int row  = mi * 16 + quad * 4 + rg;
            int grow = r0 + row;
            if (grow >= N_ROWS) continue;
            float mu = SA.red.mu[row], rs = SA.red.rs[row];
            #pragma unroll
            for (int ni = 0; ni < 4; ++ni) {
                int cidx = wv * 64 + ni * 16 + l16;
                float y = (acc[mi][ni][rg] - mu) * rs * gcol[ni] + ecol[ni];
                y += x[(size_t)grow * C + cidx];
                float g = 0.5f * y * (1.0f + erff(y * 0.70710678118654752f));
                out[(size_t)grow * C + cidx] = g;
            }
        }
    }
}

extern "C" void kernel_launch(void* const* d_in, const int* in_sizes, int n_in,
                              void* d_out, int out_size, void* d_ws, size_t ws_size,
                              hipStream_t stream) {
    const float* x  = (const float*)d_in[0];
    const int*   i1 = (const int*)d_in[1];
    const int*   i2 = (const int*)d_in[2];
    const int*   i3 = (const int*)d_in[3];
    const int*   i4 = (const int*)d_in[4];
    const float* W  = (const float*)d_in[5];
    const float* b  = (const float*)d_in[6];
    const float* gm = (const float*)d_in[7];
    const float* bt = (const float*)d_in[8];
    float* outp = (float*)d_out;
    bf16* Wt = (bf16*)d_ws;   // 20*256*64*2 = 640 KB, pre-swizzled LDS image

    wprep<<<(NCHUNK * BK * C + 255) / 256, 256, 0, stream>>>(W, Wt);
    fused<<<(N_ROWS + BM - 1) / BM, 256, 0, stream>>>(
        x, i1, i2, i3, i4, Wt, b, gm, bt, outp);
}

// Round 3
// 365.881 us; speedup vs baseline: 1.1595x; 1.1595x over previous
//
#include <hip/hip_runtime.h>

// SparseMeshConv fused kernel, R2 (MI355X / gfx950)
//   patch = [x, |a-c|, a+c, |b-d|, b+d]  (a=x[idx1], b=x[idx2], c=x[idx3], d=x[idx4])
//   y = LN(patch @ W + bias) * gamma + beta + x;  out = gelu_erf(y)
// R2 vs R1:
//  - BK=32, 40 K-chunks; A AND W double-buffered in LDS -> ONE barrier/iteration,
//    all global loads (W-DMA + gathers) issued a full iteration before their drain
//  - launch_bounds(256,3): unified reg budget 168 (acc 64 AGPR + ~80 arch) -> no spill
//    (R1's (256,4) cap = 128 forced la/lc+addr to scratch: WRITE_SIZE 100->188 MB)
//  - swizzle gs = (kk>>3) ^ ((n>>1)&3): exactly 2-way bank alias (free, m136)

#define N_ROWS   100000
#define C        256
#define BK       32
#define NCHUNK   40      // 1280 / 32
#define BM       64
#define CHUNK_EL (C * BK)   // 8192 bf16 = 16 KB
#define LN_EPS   1e-5f

typedef __bf16 bf16;
typedef bf16  bf16x8 __attribute__((ext_vector_type(8)));
typedef float f32x4  __attribute__((ext_vector_type(4)));

union BV  { bf16x8 v; bf16 h[8]; };
union FV2 { float4 q[2]; float f[8]; };

__device__ __forceinline__ void async_g2l(const void* g, void* l) {
    __builtin_amdgcn_global_load_lds(
        (const __attribute__((address_space(1))) void*)g,
        (__attribute__((address_space(3))) void*)l, 16, 0, 0);
}

// K-chunk -> original W row permutation (BK=32):
//  kc 0..7   : x slice kc            kRow = kc*32 + kk
//  kc 8..23  : u=kc-8,  h=u&1, p=u>>1 -> kRow = 256 + h*256 + p*32 + kk  (|a-c|/a+c)
//  kc 24..39 : u=kc-24, likewise      kRow = 768 + h*256 + p*32 + kk     (|b-d|/b+d)
// Wt stores bf16 in LDS-image order: [kc][n][gs][e], gs = (kk>>3) ^ ((n>>1)&3)
__global__ void wprep(const float* __restrict__ W, bf16* __restrict__ Wt) {
    int t = blockIdx.x * 256 + threadIdx.x;
    if (t >= NCHUNK * BK * C) return;          // 327680
    int n  = t & 255;                          // coalesced reads over n
    int r  = t >> 8;                           // kc*32 + kk
    int kc = r >> 5;
    int kk = r & 31;
    int kRow;
    if (kc < 8)       kRow = kc * 32 + kk;
    else if (kc < 24) { int u = kc - 8;  kRow = 256 + (u & 1) * 256 + (u >> 1) * 32 + kk; }
    else              { int u = kc - 24; kRow = 768 + (u & 1) * 256 + (u >> 1) * 32 + kk; }
    int gs = (kk >> 3) ^ ((n >> 1) & 3);
    Wt[(size_t)kc * CHUNK_EL + n * 32 + gs * 8 + (kk & 7)] = (bf16)W[(size_t)kRow * C + n];
}

__global__ __launch_bounds__(256, 3)
void fused(const float* __restrict__ x,
           const int* __restrict__ idx1, const int* __restrict__ idx2,
           const int* __restrict__ idx3, const int* __restrict__ idx4,
           const bf16* __restrict__ Wt,
           const float* __restrict__ bias,
           const float* __restrict__ gamma_, const float* __restrict__ beta_,
           float* __restrict__ out)
{
    __shared__ __align__(16) bf16 Wl[2][CHUNK_EL];      // 32768 B, swizzled images
    __shared__ __align__(16) union {
        bf16 a[2][BM * BK];                             // 8192 B, swizzled
        struct { float rsum[BM][4]; float rsq[BM][4]; float mu[BM]; float rs[BM]; } red;
    } SA;                                               // total LDS = 40960 B

    const int tid  = threadIdx.x;
    const int lane = tid & 63;
    const int wv   = tid >> 6;       // wave -> column group (wv*64)
    const int quad = lane >> 4;
    const int l16  = lane & 15;
    const int r0   = blockIdx.x * BM;

    const int r_st = tid >> 2;       // staging row 0..63
    const int q_st = tid & 3;        // 8-float eighth of the 32-col slice
    int gr_self = r0 + r_st; if (gr_self >= N_ROWS) gr_self = 0;
    const int ia = idx1[gr_self], ib = idx2[gr_self];
    const int ic = idx3[gr_self], id = idx4[gr_self];

    const int aswz = ((q_st ^ ((r_st >> 1) & 3)) << 3);     // A-tile write granule
    const int a_w_off = r_st * 32 + aswz;

    f32x4 acc[4][4] = {};
    bf16x8 hold;                     // held (a+c)/(b+d) bf16 for odd pair chunk

    // ---- prologue: chunk 0 (self slice 0) into buf 0; W chunk 0 DMA into buf 0
    {
        const float4* p = (const float4*)(x + (size_t)gr_self * C + (q_st << 3));
        FV2 u; u.q[0] = p[0]; u.q[1] = p[1];
        BV b0;
        #pragma unroll
        for (int j = 0; j < 8; ++j) b0.h[j] = (bf16)u.f[j];
        *(bf16x8*)&SA.a[0][a_w_off] = b0.v;
        #pragma unroll
        for (int j = 0; j < 4; ++j) {
            int g = j * 256 + tid;
            async_g2l(Wt + g * 8, &Wl[0][g * 8]);
        }
    }
    __syncthreads();

    for (int kc = 0; kc < NCHUNK; ++kc) {
        const int kn = kc + 1;

        // ---- issue W DMA for chunk kn into the other buffer
        if (kn < NCHUNK) {
            const bf16* wsrc = Wt + (size_t)kn * CHUNK_EL;
            bf16* wdst = Wl[kn & 1];
            #pragma unroll
            for (int j = 0; j < 4; ++j) {
                int g = j * 256 + tid;
                async_g2l(wsrc + g * 8, wdst + g * 8);
            }
        }

        // ---- issue gather/self loads for chunk kn
        FV2 la, lc;
        int mode = 0;        // 0 held/none, 1 self slice, 2 pair (diff now, sum held)
        if (kn < 8) {
            mode = 1;
            const float4* p = (const float4*)(x + (size_t)gr_self * C + (kn << 5) + (q_st << 3));
            la.q[0] = p[0]; la.q[1] = p[1];
        } else if (kn < NCHUNK) {
            int u = (kn < 24) ? (kn - 8) : (kn - 24);
            if (!(u & 1)) {
                mode = 2;
                int rA = (kn < 24) ? ia : ib;
                int rC = (kn < 24) ? ic : id;
                int off = ((u >> 1) << 5) + (q_st << 3);
                const float4* pa = (const float4*)(x + (size_t)rA * C + off);
                const float4* pc = (const float4*)(x + (size_t)rC * C + off);
                la.q[0] = pa[0]; la.q[1] = pa[1];
                lc.q[0] = pc[0]; lc.q[1] = pc[1];
            }
        }

        // ---- MFMA on buffer kc&1 (one k-step of 32)
        {
            const bf16* Ab = SA.a[kc & 1];
            const bf16* Wb = Wl[kc & 1];
            bf16x8 af[4], wf[4];
            #pragma unroll
            for (int mi = 0; mi < 4; ++mi) {
                int m = mi * 16 + l16;
                af[mi] = *(const bf16x8*)&Ab[m * 32 + ((quad ^ ((m >> 1) & 3)) << 3)];
            }
            #pragma unroll
            for (int ni = 0; ni < 4; ++ni) {
                int n = wv * 64 + ni * 16 + l16;
                wf[ni] = *(const bf16x8*)&Wb[n * 32 + ((quad ^ ((n >> 1) & 3)) << 3)];
            }
            #pragma unroll
            for (int mi = 0; mi < 4; ++mi)
                #pragma unroll
                for (int ni = 0; ni < 4; ++ni)
                    acc[mi][ni] = __builtin_amdgcn_mfma_f32_16x16x32_bf16(
                        af[mi], wf[ni], acc[mi][ni], 0, 0, 0);
        }

        // ---- convert + stage chunk kn into the other A buffer (waits on loads here)
        if (kn < NCHUNK) {
            BV sv;
            if (mode == 1) {
                #pragma unroll
                for (int j = 0; j < 8; ++j) sv.h[j] = (bf16)la.f[j];
            } else if (mode == 2) {
                BV hs;
                #pragma unroll
                for (int j = 0; j < 8; ++j) {
                    sv.h[j] = (bf16)fabsf(la.f[j] - lc.f[j]);
                    hs.h[j] = (bf16)(la.f[j] + lc.f[j]);
                }
                hold = hs.v;
            } else {
                sv.v = hold;
            }
            *(bf16x8*)&SA.a[kn & 1][a_w_off] = sv.v;
            __syncthreads();   // the ONLY barrier: drains this iter's DMA + A writes
        }
    }

    // ---- epilogue: +bias, LN stats, normalize, residual, exact GELU
    float bcol[4], gcol[4], ecol[4];
    #pragma unroll
    for (int ni = 0; ni < 4; ++ni) {
        int cidx = wv * 64 + ni * 16 + l16;
        bcol[ni] = bias[cidx]; gcol[ni] = gamma_[cidx]; ecol[ni] = beta_[cidx];
    }
    #pragma unroll
    for (int mi = 0; mi < 4; ++mi)
        #pragma unroll
        for (int ni = 0; ni < 4; ++ni)
            #pragma unroll
            for (int rg = 0; rg < 4; ++rg)
                acc[mi][ni][rg] += bcol[ni];

    #pragma unroll
    for (int mi = 0; mi < 4; ++mi) {
        #pragma unroll
        for (int rg = 0; rg < 4; ++rg) {
            float s = 0.f, q = 0.f;
            #pragma unroll
            for (int ni = 0; ni < 4; ++ni) {
                float y = acc[mi][ni][rg];
                s += y; q += y * y;
            }
            #pragma unroll
            for (int m = 1; m <= 8; m <<= 1) {
                s += __shfl_xor(s, m, 64);
                q += __shfl_xor(q, m, 64);
            }
            if (l16 == 0) {
                int row = mi * 16 + quad * 4 + rg;
                SA.red.rsum[row][wv] = s;
                SA.red.rsq [row][wv] = q;
            }
        }
    }
    __syncthreads();
    if (tid < BM) {
        float s  = SA.red.rsum[tid][0] + SA.red.rsum[tid][1] + SA.red.rsum[tid][2] + SA.red.rsum[tid][3];
        float q  = SA.red.rsq [tid][0] + SA.red.rsq [tid][1] + SA.red.rsq [tid][2] + SA.red.rsq [tid][3];
        float mu = s * (1.0f / C);
        float var = q * (1.0f / C) - mu * mu;
        SA.red.mu[tid] = mu;
        SA.red.rs[tid] = rsqrtf(var + LN_EPS);
    }
    __syncthreads();

    #pragma unroll
    for (int mi = 0; mi < 4; ++mi) {
        #pragma unroll
        for (int rg = 0; rg < 4; ++rg) {
            int row  = mi * 16 + quad * 4 + rg;
            int grow = r0 + row;
            if (grow >= N_ROWS) continue;
            float mu = SA.red.mu[row], rs = SA.red.rs[row];
            #pragma unroll
            for (int ni = 0; ni < 4; ++ni) {
                int cidx = wv * 64 + ni * 16 + l16;
                float y = (acc[mi][ni][rg] - mu) * rs * gcol[ni] + ecol[ni];
                y += x[(size_t)grow * C + cidx];
                float g = 0.5f * y * (1.0f + erff(y * 0.70710678118654752f));
                out[(size_t)grow * C + cidx] = g;
            }
        }
    }
}

extern "C" void kernel_launch(void* const* d_in, const int* in_sizes, int n_in,
                              void* d_out, int out_size, void* d_ws, size_t ws_size,
                              hipStream_t stream) {
    const float* x  = (const float*)d_in[0];
    const int*   i1 = (const int*)d_in[1];
    const int*   i2 = (const int*)d_in[2];
    const int*   i3 = (const int*)d_in[3];
    const int*   i4 = (const int*)d_in[4];
    const float* W  = (const float*)d_in[5];
    const float* b  = (const float*)d_in[6];
    const float* gm = (const float*)d_in[7];
    const float* bt = (const float*)d_in[8];
    float* outp = (float*)d_out;
    bf16* Wt = (bf16*)d_ws;   // 40*8192*2 = 640 KB, pre-swizzled LDS images

    wprep<<<(NCHUNK * BK * C + 255) / 256, 256, 0, stream>>>(W, Wt);
    fused<<<(N_ROWS + BM - 1) / BM, 256, 0, stream>>>(
        x, i1, i2, i3, i4, Wt, b, gm, bt, outp);
}